// Round 10
// baseline (152.968 us; speedup 1.0000x reference)
//
#include <hip/hip_runtime.h>

typedef _Float16 f16;
typedef f16 f16x4 __attribute__((ext_vector_type(4)));
typedef f16 f16x8 __attribute__((ext_vector_type(8)));
typedef float f32x4 __attribute__((ext_vector_type(4)));

// state_embed (256,512) f32 | action_feats (256,1000,64) f32 | W1 (576,256) | b1 (256)
// W2 (256,128) | b2 (128) | W3 (128,1) | b3 (1)  -> out (256,1000) f32

#define AF_STRIDE 72    // 64+8 f16 = 36 dwords/row
#define H1_STRIDE 264   // 256+8 f16 = 132 dwords/row

// ---------- prep: pack W1a^T (A-frag), W2 (B-frag), compute h_state ----------
// A-frag (16x16x32): lane L holds A[m=L&15][k=(L>>4)*8+j], j=0..7
// B-frag:            lane L holds B[k=(L>>4)*8+j][n=L&15]
__global__ __launch_bounds__(256) void prep_kernel(const float* __restrict__ W1,
                                                   const float* __restrict__ W2,
                                                   const float* __restrict__ state,
                                                   const float* __restrict__ b1,
                                                   f16* __restrict__ pw1at,
                                                   f16* __restrict__ pw2,
                                                   float* __restrict__ hstate) {
    __shared__ float srow[512];
    int blk = blockIdx.x;
    int tid = threadIdx.x;
    if (blk < 24) {
        int idx = blk * 256 + tid;              // 0..6143
        int F = idx >> 6;                       // fragment id 0..95
        int L = idx & 63;
        int q = L >> 4, c = L & 15;
        f16x8 v;
        if (F < 32) {                           // pw1at: M=256h (mt 0..15), K=64f (kt 0..1)
            int mt = F >> 1, kt = F & 1;
            #pragma unroll
            for (int j = 0; j < 8; ++j) {
                int f = kt * 32 + q * 8 + j;
                v[j] = (f16)W1[(size_t)(512 + f) * 256 + mt * 16 + c];
            }
            *(f16x8*)(pw1at + ((size_t)F * 64 + L) * 8) = v;
        } else {                                // pw2: K=256 (kt 0..7), N=128 (nt 0..7)
            int F2 = F - 32;
            int nt = F2 >> 3, kt = F2 & 7;
            #pragma unroll
            for (int j = 0; j < 8; ++j) {
                int k = kt * 32 + q * 8 + j;
                v[j] = (f16)W2[(size_t)k * 128 + nt * 16 + c];
            }
            *(f16x8*)(pw2 + ((size_t)F2 * 64 + L) * 8) = v;
        }
    } else {
        int b = blk - 24;                       // one batch row per block (fp32 exact)
        srow[tid] = state[(size_t)b * 512 + tid];
        srow[tid + 256] = state[(size_t)b * 512 + 256 + tid];
        __syncthreads();
        float a0 = 0.f, a1 = 0.f;
        #pragma unroll 8
        for (int f = 0; f < 512; f += 2) {
            a0 = fmaf(srow[f],     W1[(size_t)f * 256 + tid],       a0);
            a1 = fmaf(srow[f + 1], W1[(size_t)(f + 1) * 256 + tid], a1);
        }
        hstate[(size_t)b * 256 + tid] = a0 + a1 + b1[tid];
    }
}

// ---------- fused MLP: 2 tiles x 64 actions/block, h-split waves ----------
// Occupancy evidence R4-R8: achieved blocks/CU == declared launch_bounds 2nd arg.
// So declare 3 and make the body genuinely fit 512/3 ~ 168 unified regs:
//  - chunked layer-3 tail (live 8 vs 30)
//  - a1f loaded per-tile (rematerializable from L2 under pressure, not scratch-spilled)
//  - LDS 52224 (lds3 aliases afs2 head; t=1 reads only afs2 rows 64..127) -> 3 blocks/CU
// Spill tripwire: WRITE_SIZE must stay ~1 MB.
__global__ __launch_bounds__(256, 3) void fused_kernel(const float* __restrict__ afeat,
                                                       const float* __restrict__ hstate,
                                                       const f16* __restrict__ pw1at,
                                                       const f16* __restrict__ pw2,
                                                       const float* __restrict__ b2,
                                                       const float* __restrict__ W3,
                                                       const float* __restrict__ b3,
                                                       float* __restrict__ out) {
    __shared__ f16 afs2[128 * AF_STRIDE];   // 18432 B
    __shared__ f16 h1s[64 * H1_STRIDE];     // 33792 B  => 52224 total
    float* lds3 = (float*)afs2;             // 64*6 f32 = 1536 B, aliases afs2 rows 0..10

    int tid = threadIdx.x;
    int w = tid >> 6;                 // wave 0..3
    int L = tid & 63;
    int q = L >> 4, c = L & 15;
    int r0g = blockIdx.x * 128;       // first global action row of this block's 2 tiles

    // ---- stage both tiles: 128 rows x 64 f32 -> f16 LDS ----
    #pragma unroll
    for (int i = 0; i < 4; ++i) {
        int id = i * 256 + tid;               // 32B-chunk id 0..1023
        int row = id >> 3, c32 = id & 7;
        const float* p = afeat + (size_t)(r0g + row) * 64 + c32 * 8;
        f32x4 lo = *(const f32x4*)p;
        f32x4 hi = *(const f32x4*)(p + 4);
        f16x8 v;
        v[0] = (f16)lo[0]; v[1] = (f16)lo[1]; v[2] = (f16)lo[2]; v[3] = (f16)lo[3];
        v[4] = (f16)hi[0]; v[5] = (f16)hi[1]; v[6] = (f16)hi[2]; v[7] = (f16)hi[3];
        *(f16x8*)(afs2 + row * AF_STRIDE + c32 * 8) = v;
    }

    float b3v = b3[0];
    float b2v[2], w3v[2];
    #pragma unroll
    for (int ntl = 0; ntl < 2; ++ntl) {
        int col = (w * 2 + ntl) * 16 + c;
        b2v[ntl] = b2[col];
        w3v[ntl] = W3[col];
    }
    __syncthreads();

    for (int t = 0; t < 2; ++t) {
        int r0 = r0g + t * 64;
        int b0i = r0 / 1000;
        int boundary = (b0i + 1) * 1000;
        int b1i = b0i < 255 ? b0i + 1 : 255;

        // ---- W1a^T A-frags for this tile (loaded per-tile: rematerializable) ----
        f16x8 a1f[4][2];
        #pragma unroll
        for (int i = 0; i < 4; ++i)
            #pragma unroll
            for (int kt = 0; kt < 2; ++kt)
                a1f[i][kt] = *(const f16x8*)(pw1at + ((size_t)((4 * w + i) * 2 + kt) * 64 + L) * 8);

        // ---- GEMM1 B-frags (afeat^T) from LDS ----
        f16x8 bf[4][2];
        #pragma unroll
        for (int nt = 0; nt < 4; ++nt)
            #pragma unroll
            for (int kt = 0; kt < 2; ++kt)
                bf[nt][kt] = *(const f16x8*)(afs2 + (t * 64 + nt * 16 + c) * AF_STRIDE + kt * 32 + q * 8);

        // ---- GEMM1 interleaved with epilogue-1: acc live = 16 regs per i-slice ----
        #pragma unroll
        for (int i = 0; i < 4; ++i) {
            f32x4 acc[4];
            #pragma unroll
            for (int nt = 0; nt < 4; ++nt) {
                acc[nt] = (f32x4){0.f, 0.f, 0.f, 0.f};
                #pragma unroll
                for (int kt = 0; kt < 2; ++kt)
                    acc[nt] = __builtin_amdgcn_mfma_f32_16x16x32_f16(
                        a1f[i][kt], bf[nt][kt], acc[nt], 0, 0, 0);
            }
            int hbase = (4 * w + i) * 16 + q * 4;
            f32x4 hsA = *(const f32x4*)(hstate + (size_t)b0i * 256 + hbase);
            f32x4 hsB = *(const f32x4*)(hstate + (size_t)b1i * 256 + hbase);
            #pragma unroll
            for (int nt = 0; nt < 4; ++nt) {
                bool sel = (r0 + nt * 16 + c) >= boundary;
                f16x4 hv;
                #pragma unroll
                for (int reg = 0; reg < 4; ++reg) {
                    float v = acc[nt][reg] + (sel ? hsB[reg] : hsA[reg]);
                    v = v > 0.f ? v : 0.f;
                    hv[reg] = (f16)v;
                }
                *(f16x4*)(h1s + (nt * 16 + c) * H1_STRIDE + hbase) = hv;
            }
        }
        __syncthreads();   // B1: h1s ready (also orders prior tile's lds3 reads)

        // ---- GEMM2: h2(64x128) = h1 @ W2; wave w owns n-slice [32w, 32w+32);
        //      W2 B-frags streamed from L2 each kt ----
        f32x4 acc2[4][2];
        #pragma unroll
        for (int rb = 0; rb < 4; ++rb) {
            acc2[rb][0] = (f32x4){0.f, 0.f, 0.f, 0.f};
            acc2[rb][1] = (f32x4){0.f, 0.f, 0.f, 0.f};
        }
        #pragma unroll
        for (int kt = 0; kt < 8; ++kt) {
            f16x8 a2[4];
            #pragma unroll
            for (int rb = 0; rb < 4; ++rb)
                a2[rb] = *(const f16x8*)(h1s + (rb * 16 + c) * H1_STRIDE + kt * 32 + q * 8);
            #pragma unroll
            for (int ntl = 0; ntl < 2; ++ntl) {
                f16x8 bfr = *(const f16x8*)(pw2 + ((size_t)((w * 2 + ntl) * 8 + kt) * 64 + L) * 8);
                #pragma unroll
                for (int rb = 0; rb < 4; ++rb)
                    acc2[rb][ntl] = __builtin_amdgcn_mfma_f32_16x16x32_f16(
                        a2[rb], bfr, acc2[rb][ntl], 0, 0, 0);
            }
        }

        // ---- layer 3, chunked per rb: 4 values, 5 shuffles, live ~8 regs ----
        #pragma unroll
        for (int rb = 0; rb < 4; ++rb) {
            float pr[4];
            #pragma unroll
            for (int reg = 0; reg < 4; ++reg) {
                float v0 = acc2[rb][0][reg] + b2v[0]; v0 = v0 > 0.f ? v0 : 0.f;
                float v1 = acc2[rb][1][reg] + b2v[1]; v1 = v1 > 0.f ? v1 : 0.f;
                pr[reg] = fmaf(v0, w3v[0], v1 * w3v[1]);
            }
            // stage A (c bit0): lane keeps j with j&1 == c&1
            float e0 = (c & 1) ? pr[0] : pr[1];
            float k0 = (c & 1) ? pr[1] : pr[0];
            float e1 = (c & 1) ? pr[2] : pr[3];
            float k1 = (c & 1) ? pr[3] : pr[2];
            float a0 = k0 + __shfl_xor(e0, 1);
            float a1 = k1 + __shfl_xor(e1, 1);
            // stage B (c bit1): keep j with (j>>1)&1 == (c>>1)&1  -> j = c&3
            float e2 = (c & 2) ? a0 : a1;
            float k2 = (c & 2) ? a1 : a0;
            float s  = k2 + __shfl_xor(e2, 2);
            // stages C,D: sum over c bits 2,3
            s += __shfl_xor(s, 4);
            s += __shfl_xor(s, 8);
            if ((c & 12) == 0)
                lds3[(rb * 16 + q * 4 + (c & 3)) * 6 + w] = s;
        }
        __syncthreads();   // B2: lds3 ready, h1s reads done

        if (tid < 64) {
            const float* pm = lds3 + tid * 6;
            out[r0 + tid] = pm[0] + pm[1] + pm[2] + pm[3] + b3v;
        }
        // no extra barrier: t=1 reads afs2 rows 64..127 (disjoint from lds3) and
        // t=1's lds3 writes happen after B1(t=1), which orders these reads.
    }
}

extern "C" void kernel_launch(void* const* d_in, const int* in_sizes, int n_in,
                              void* d_out, int out_size, void* d_ws, size_t ws_size,
                              hipStream_t stream) {
    const float* state = (const float*)d_in[0];
    const float* afeat = (const float*)d_in[1];
    const float* W1    = (const float*)d_in[2];
    const float* b1    = (const float*)d_in[3];
    const float* W2    = (const float*)d_in[4];
    const float* b2    = (const float*)d_in[5];
    const float* W3    = (const float*)d_in[6];
    const float* b3    = (const float*)d_in[7];
    float* out = (float*)d_out;

    // ws: hstate 256KB | pw1at 32KB (16384 f16) | pw2 64KB (32768 f16)
    float* hstate = (float*)d_ws;
    f16* pw1at = (f16*)((char*)d_ws + 65536 * sizeof(float));
    f16* pw2   = pw1at + 16384;

    prep_kernel<<<280, 256, 0, stream>>>(W1, W2, state, b1, pw1at, pw2, hstate);
    fused_kernel<<<2000, 256, 0, stream>>>(afeat, hstate, pw1at, pw2, b2, W3, b3, out);
}

// Round 11
// 147.193 us; speedup vs baseline: 1.0392x; 1.0392x over previous
//
#include <hip/hip_runtime.h>

typedef _Float16 f16;
typedef f16 f16x4 __attribute__((ext_vector_type(4)));
typedef f16 f16x8 __attribute__((ext_vector_type(8)));
typedef float f32x4 __attribute__((ext_vector_type(4)));

// state_embed (256,512) f32 | action_feats (256,1000,64) f32 | W1 (576,256) | b1 (256)
// W2 (256,128) | b2 (128) | W3 (128,1) | b3 (1)  -> out (256,1000) f32

#define AF_STRIDE 72    // 64+8 f16 = 36 dwords/row
#define H1_STRIDE 264   // 256+8 f16 = 132 dwords/row

// ---------- prep: pack W1a^T (A-frag), W2 (B-frag), compute h_state ----------
// A-frag (16x16x32): lane L holds A[m=L&15][k=(L>>4)*8+j], j=0..7
// B-frag:            lane L holds B[k=(L>>4)*8+j][n=L&15]
__global__ __launch_bounds__(256) void prep_kernel(const float* __restrict__ W1,
                                                   const float* __restrict__ W2,
                                                   const float* __restrict__ state,
                                                   const float* __restrict__ b1,
                                                   f16* __restrict__ pw1at,
                                                   f16* __restrict__ pw2,
                                                   float* __restrict__ hstate) {
    __shared__ float srow[512];
    int blk = blockIdx.x;
    int tid = threadIdx.x;
    if (blk < 24) {
        int idx = blk * 256 + tid;              // 0..6143
        int F = idx >> 6;                       // fragment id 0..95
        int L = idx & 63;
        int q = L >> 4, c = L & 15;
        f16x8 v;
        if (F < 32) {                           // pw1at: M=256h (mt 0..15), K=64f (kt 0..1)
            int mt = F >> 1, kt = F & 1;
            #pragma unroll
            for (int j = 0; j < 8; ++j) {
                int f = kt * 32 + q * 8 + j;
                v[j] = (f16)W1[(size_t)(512 + f) * 256 + mt * 16 + c];
            }
            *(f16x8*)(pw1at + ((size_t)F * 64 + L) * 8) = v;
        } else {                                // pw2: K=256 (kt 0..7), N=128 (nt 0..7)
            int F2 = F - 32;
            int nt = F2 >> 3, kt = F2 & 7;
            #pragma unroll
            for (int j = 0; j < 8; ++j) {
                int k = kt * 32 + q * 8 + j;
                v[j] = (f16)W2[(size_t)k * 128 + nt * 16 + c];
            }
            *(f16x8*)(pw2 + ((size_t)F2 * 64 + L) * 8) = v;
        }
    } else {
        int b = blk - 24;                       // one batch row per block (fp32 exact)
        srow[tid] = state[(size_t)b * 512 + tid];
        srow[tid + 256] = state[(size_t)b * 512 + 256 + tid];
        __syncthreads();
        float a0 = 0.f, a1 = 0.f;
        #pragma unroll 8
        for (int f = 0; f < 512; f += 2) {
            a0 = fmaf(srow[f],     W1[(size_t)f * 256 + tid],       a0);
            a1 = fmaf(srow[f + 1], W1[(size_t)(f + 1) * 256 + tid], a1);
        }
        hstate[(size_t)b * 256 + tid] = a0 + a1 + b1[tid];
    }
}

// ---------- fused MLP: 512 threads (8 waves), 2 tiles x 64 actions per block ----------
// Occupancy history: 4-wave body needs ~208 regs -> 2 waves/SIMD; every attempt to
// cap it to 3 waves spilled (R5/R7/R9: WRITE_SIZE 95/30/29 MB). Fix: split the same
// block work over 8 smaller waves — per-wave state: GEMM1 a1f 16 + bf 32 + acc 16;
// GEMM2 acc2 16 + a2 16 + one streamed pw2 frag. Peak ~100 regs < 128, so
// __launch_bounds__(512,2) (=> 4 waves/SIMD, 16 waves/CU) should hold w/o spill.
__global__ __launch_bounds__(512, 2) void fused_kernel(const float* __restrict__ afeat,
                                                       const float* __restrict__ hstate,
                                                       const f16* __restrict__ pw1at,
                                                       const f16* __restrict__ pw2,
                                                       const float* __restrict__ b2,
                                                       const float* __restrict__ W3,
                                                       const float* __restrict__ b3,
                                                       float* __restrict__ out) {
    __shared__ f16 afs2[128 * AF_STRIDE];   // 18432 B — 2 tiles of action_feats (f16)
    __shared__ f16 h1s[64 * H1_STRIDE];     // 33792 B
    __shared__ float lds3[64 * 8];          //  2048 B  => 54272 B total

    int tid = threadIdx.x;
    int w = tid >> 6;                 // wave 0..7
    int L = tid & 63;
    int q = L >> 4, c = L & 15;
    int r0g = blockIdx.x * 128;       // first global action row of this block's 2 tiles

    // ---- stage both tiles: 128 rows x 64 f32 -> f16 LDS ----
    #pragma unroll
    for (int i = 0; i < 2; ++i) {
        int id = i * 512 + tid;               // 32B-chunk id 0..1023
        int row = id >> 3, c32 = id & 7;
        const float* p = afeat + (size_t)(r0g + row) * 64 + c32 * 8;
        f32x4 lo = *(const f32x4*)p;
        f32x4 hi = *(const f32x4*)(p + 4);
        f16x8 v;
        v[0] = (f16)lo[0]; v[1] = (f16)lo[1]; v[2] = (f16)lo[2]; v[3] = (f16)lo[3];
        v[4] = (f16)hi[0]; v[5] = (f16)hi[1]; v[6] = (f16)hi[2]; v[7] = (f16)hi[3];
        *(f16x8*)(afs2 + row * AF_STRIDE + c32 * 8) = v;
    }

    float b3v = b3[0];
    float b2v = b2[w * 16 + c];       // wave w owns h2 cols [16w, 16w+16)
    float w3v = W3[w * 16 + c];
    __syncthreads();

    for (int t = 0; t < 2; ++t) {
        int r0 = r0g + t * 64;
        int b0i = r0 / 1000;
        int boundary = (b0i + 1) * 1000;
        int b1i = b0i < 255 ? b0i + 1 : 255;

        // ---- W1a^T A-frags: wave w owns h-slice [32w, 32w+32): mt = 2w+i ----
        f16x8 a1f[2][2];
        #pragma unroll
        for (int i = 0; i < 2; ++i)
            #pragma unroll
            for (int kt = 0; kt < 2; ++kt)
                a1f[i][kt] = *(const f16x8*)(pw1at + ((size_t)((2 * w + i) * 2 + kt) * 64 + L) * 8);

        // ---- GEMM1 B-frags (afeat^T) from LDS: all 64 actions of tile t ----
        f16x8 bf[4][2];
        #pragma unroll
        for (int nt = 0; nt < 4; ++nt)
            #pragma unroll
            for (int kt = 0; kt < 2; ++kt)
                bf[nt][kt] = *(const f16x8*)(afs2 + (t * 64 + nt * 16 + c) * AF_STRIDE + kt * 32 + q * 8);

        // ---- GEMM1 interleaved with epilogue-1 (acc live = 16 per i-slice) ----
        #pragma unroll
        for (int i = 0; i < 2; ++i) {
            f32x4 acc[4];
            #pragma unroll
            for (int nt = 0; nt < 4; ++nt) {
                acc[nt] = (f32x4){0.f, 0.f, 0.f, 0.f};
                #pragma unroll
                for (int kt = 0; kt < 2; ++kt)
                    acc[nt] = __builtin_amdgcn_mfma_f32_16x16x32_f16(
                        a1f[i][kt], bf[nt][kt], acc[nt], 0, 0, 0);
            }
            int hbase = (2 * w + i) * 16 + q * 4;
            f32x4 hsA = *(const f32x4*)(hstate + (size_t)b0i * 256 + hbase);
            f32x4 hsB = *(const f32x4*)(hstate + (size_t)b1i * 256 + hbase);
            #pragma unroll
            for (int nt = 0; nt < 4; ++nt) {
                bool sel = (r0 + nt * 16 + c) >= boundary;
                f16x4 hv;
                #pragma unroll
                for (int reg = 0; reg < 4; ++reg) {
                    float v = acc[nt][reg] + (sel ? hsB[reg] : hsA[reg]);
                    v = v > 0.f ? v : 0.f;
                    hv[reg] = (f16)v;
                }
                *(f16x4*)(h1s + (nt * 16 + c) * H1_STRIDE + hbase) = hv;
            }
        }
        __syncthreads();   // B1: h1s ready (all 256 h columns from 8 waves)

        // ---- GEMM2: wave w owns n-slice [16w, 16w+16): one pw2 frag per kt ----
        f32x4 acc2[4];
        #pragma unroll
        for (int rb = 0; rb < 4; ++rb) acc2[rb] = (f32x4){0.f, 0.f, 0.f, 0.f};
        #pragma unroll
        for (int kt = 0; kt < 8; ++kt) {
            f16x8 a2[4];
            #pragma unroll
            for (int rb = 0; rb < 4; ++rb)
                a2[rb] = *(const f16x8*)(h1s + (rb * 16 + c) * H1_STRIDE + kt * 32 + q * 8);
            f16x8 bfr = *(const f16x8*)(pw2 + ((size_t)(w * 8 + kt) * 64 + L) * 8);
            #pragma unroll
            for (int rb = 0; rb < 4; ++rb)
                acc2[rb] = __builtin_amdgcn_mfma_f32_16x16x32_f16(a2[rb], bfr, acc2[rb], 0, 0, 0);
        }

        // ---- layer 3, chunked per rb: relu+bias+dot over this wave's 16 cols ----
        #pragma unroll
        for (int rb = 0; rb < 4; ++rb) {
            float pr[4];
            #pragma unroll
            for (int reg = 0; reg < 4; ++reg) {
                float v0 = acc2[rb][reg] + b2v;
                v0 = v0 > 0.f ? v0 : 0.f;
                pr[reg] = v0 * w3v;
            }
            // reduce over c while distributing the 4 reg-rows to lanes c&3
            float e0 = (c & 1) ? pr[0] : pr[1];
            float k0 = (c & 1) ? pr[1] : pr[0];
            float e1 = (c & 1) ? pr[2] : pr[3];
            float k1 = (c & 1) ? pr[3] : pr[2];
            float a0 = k0 + __shfl_xor(e0, 1);
            float a1 = k1 + __shfl_xor(e1, 1);
            float e2 = (c & 2) ? a0 : a1;
            float k2 = (c & 2) ? a1 : a0;
            float s  = k2 + __shfl_xor(e2, 2);
            s += __shfl_xor(s, 4);
            s += __shfl_xor(s, 8);
            if ((c & 12) == 0)
                lds3[(rb * 16 + q * 4 + (c & 3)) * 8 + w] = s;
        }
        __syncthreads();   // B2: lds3 ready, h1s reads done

        if (tid < 64) {
            const float* pm = lds3 + tid * 8;
            f32x4 s0 = *(const f32x4*)pm;
            f32x4 s1 = *(const f32x4*)(pm + 4);
            out[r0 + tid] = s0[0] + s0[1] + s0[2] + s0[3] + s1[0] + s1[1] + s1[2] + s1[3] + b3v;
        }
        // next tile: GEMM1(t=1) reads afs2 rows 64..127 and rewrites h1s only after
        // B2 above; lds3 next written only after B1(t=1). No extra barrier needed.
    }
}

extern "C" void kernel_launch(void* const* d_in, const int* in_sizes, int n_in,
                              void* d_out, int out_size, void* d_ws, size_t ws_size,
                              hipStream_t stream) {
    const float* state = (const float*)d_in[0];
    const float* afeat = (const float*)d_in[1];
    const float* W1    = (const float*)d_in[2];
    const float* b1    = (const float*)d_in[3];
    const float* W2    = (const float*)d_in[4];
    const float* b2    = (const float*)d_in[5];
    const float* W3    = (const float*)d_in[6];
    const float* b3    = (const float*)d_in[7];
    float* out = (float*)d_out;

    // ws: hstate 256KB | pw1at 32KB (16384 f16) | pw2 64KB (32768 f16)
    float* hstate = (float*)d_ws;
    f16* pw1at = (f16*)((char*)d_ws + 65536 * sizeof(float));
    f16* pw2   = pw1at + 16384;

    prep_kernel<<<280, 256, 0, stream>>>(W1, W2, state, b1, pw1at, pw2, hstate);
    fused_kernel<<<2000, 512, 0, stream>>>(afeat, hstate, pw1at, pw2, b2, W3, b3, out);
}